// Round 3
// baseline (1164.023 us; speedup 1.0000x reference)
//
#include <hip/hip_runtime.h>
#include <math.h>

#define N_NODES 100000
#define N_EDGES 3200000
#define N_TOT   (N_EDGES + N_NODES)
#define F_IN    512
#define HID     16
#define NCLS    32
#define NEG_SLOPE 0.2f

#define BSH   7                       // bucket shift: 128 nodes per bucket
#define NBKT  ((N_NODES + 127) / 128) // 782
#define SRC_MASK 0x1FFFF              // 17 bits, N_NODES < 131072

// ---------- edge dtype detection (int64 vs int32) ----------
__global__ __launch_bounds__(64) void k_detect(const int* __restrict__ ei,
                                               int* __restrict__ flag) {
  int v = ei[2 * threadIdx.x + 1];
  unsigned long long m = __ballot(v != 0);
  if (threadIdx.x == 0) *flag = (m == 0ull) ? 1 : 0;  // 1 => int64 layout
}

// ---------- bucket counts via per-block LDS histogram ----------
__global__ __launch_bounds__(256) void k_bcount(const int* __restrict__ ei,
                                                const int* __restrict__ flag,
                                                int* __restrict__ bcnt) {
  __shared__ int h[NBKT];
  for (int i = threadIdx.x; i < NBKT; i += 256) h[i] = 0;
  __syncthreads();
  int fl = *flag;
  int stride = gridDim.x * 256;
  for (int e = blockIdx.x * 256 + threadIdx.x; e < N_EDGES; e += stride) {
    int d = fl ? ei[2 * (N_EDGES + e)] : ei[N_EDGES + e];
    d = min(max(d, 0), N_NODES - 1);
    atomicAdd(&h[d >> BSH], 1);
  }
  __syncthreads();
  for (int i = threadIdx.x; i < NBKT; i += 256)
    if (h[i]) atomicAdd(&bcnt[i], h[i]);
}

// ---------- scan bucket counts (256 threads, 4 buckets/thread) ----------
__global__ __launch_bounds__(256) void k_bscan(const int* __restrict__ bcnt,
                                               int* __restrict__ bbase,
                                               int* __restrict__ cbase,
                                               int* __restrict__ bcur,
                                               int* __restrict__ offs) {
  __shared__ int s1[256], s2[256];
  int t = threadIdx.x;
  int c[4], vn[4];
  int sum1 = 0, sum2 = 0;
#pragma unroll
  for (int j = 0; j < 4; ++j) {
    int idx = t * 4 + j;
    int cc = 0, vv = 0;
    if (idx < NBKT) {
      cc = bcnt[idx];
      int lo = idx << BSH;
      vv = min(128, N_NODES - lo);     // valid nodes in bucket (self loops)
    }
    c[j] = cc; vn[j] = vv;
    sum1 += cc; sum2 += cc + vv;
  }
  int o1 = sum1, o2 = sum2;
  s1[t] = sum1; s2[t] = sum2;
  __syncthreads();
  for (int off = 1; off < 256; off <<= 1) {
    int a = 0, b = 0;
    if (t >= off) { a = s1[t - off]; b = s2[t - off]; }
    __syncthreads();
    s1[t] += a; s2[t] += b;
    __syncthreads();
  }
  int r1 = s1[t] - o1;  // exclusive prefix for this thread's first bucket
  int r2 = s2[t] - o2;
#pragma unroll
  for (int j = 0; j < 4; ++j) {
    int idx = t * 4 + j;
    if (idx < NBKT) {
      bbase[idx] = r1; bcur[idx] = r1; cbase[idx] = r2;
      r1 += c[j];
      r2 += c[j] + vn[j];
    }
  }
  if (t == 0) offs[N_NODES] = N_TOT;
}

// ---------- bin edges by dst bucket (packed: (dst&127)<<17 | src) ----------
__global__ __launch_bounds__(256) void k_bin(const int* __restrict__ ei,
                                             const int* __restrict__ flag,
                                             int* __restrict__ bcur,
                                             int* __restrict__ binned) {
  int e = blockIdx.x * 256 + threadIdx.x;
  if (e >= N_EDGES) return;
  int fl = *flag;
  int s, d;
  if (fl) { s = ei[2 * e]; d = ei[2 * (N_EDGES + e)]; }
  else    { s = ei[e];     d = ei[N_EDGES + e]; }
  s = min(max(s, 0), N_NODES - 1);
  d = min(max(d, 0), N_NODES - 1);
  int p = atomicAdd(&bcur[d >> BSH], 1);
  p = min(max(p, 0), N_EDGES - 1);
  binned[p] = ((d & 127) << 17) | s;
}

// ---------- per-bucket counting sort in LDS -> CSR offs + srcS ----------
__global__ __launch_bounds__(256) void k_bucket(const int* __restrict__ bcnt,
                                                const int* __restrict__ bbase,
                                                const int* __restrict__ cbase,
                                                const int* __restrict__ binned,
                                                int* __restrict__ offs,
                                                int* __restrict__ srcS) {
  __shared__ int cnt[128], cur[128], sc[128];
  __shared__ int hdr[3];
  int b = blockIdx.x, t = threadIdx.x;
  if (t == 0) {
    hdr[0] = min(max(bcnt[b], 0), N_EDGES);
    hdr[1] = min(max(bbase[b], 0), N_EDGES - 1);
    hdr[2] = min(max(cbase[b], 0), N_TOT - 1);
  }
  if (t < 128) cnt[t] = 0;
  __syncthreads();
  int nb = hdr[0], base = hdr[1], cb = hdr[2];

  for (int i = t; i < nb; i += 256) {
    int pk = binned[min(base + i, N_EDGES - 1)];
    atomicAdd(&cnt[(pk >> 17) & 127], 1);
  }
  __syncthreads();

  int node = (b << BSH) + t;
  int myv = 0;
  if (t < 128) myv = (node < N_NODES) ? cnt[t] + 1 : 0;  // +1 self loop
  if (t < 128) sc[t] = myv;
  __syncthreads();
  for (int off = 1; off < 128; off <<= 1) {
    int v = 0;
    if (t < 128 && t >= off) v = sc[t - off];
    __syncthreads();
    if (t < 128) sc[t] += v;
    __syncthreads();
  }
  if (t < 128 && node < N_NODES) {
    int lofs = sc[t] - myv;          // exclusive prefix within bucket
    int o = min(cb + lofs, N_TOT - 1);
    offs[node] = o;
    srcS[o] = node;                  // self-loop occupies slot 0
    cur[t] = lofs + 1;
  }
  __syncthreads();

  for (int i = t; i < nb; i += 256) {
    int pk = binned[min(base + i, N_EDGES - 1)];
    int p = atomicAdd(&cur[(pk >> 17) & 127], 1);
    srcS[min(cb + p, N_TOT - 1)] = pk & SRC_MASK;
  }
}

// ---------- layer GEMMs (thread-per-row; W uniform -> s_load path) ----------
__global__ __launch_bounds__(256) void k_gemm1(const float* __restrict__ x,
                                               const float* __restrict__ W,
                                               const float* __restrict__ atts,
                                               const float* __restrict__ attd,
                                               float* __restrict__ h,
                                               float* __restrict__ as_,
                                               float* __restrict__ ad_) {
  int row = blockIdx.x * 256 + threadIdx.x;
  if (row >= N_NODES) return;
  const float4* xr = (const float4*)(x + (size_t)row * F_IN);
  float acc[HID];
#pragma unroll
  for (int f = 0; f < HID; ++f) acc[f] = 0.f;
  for (int k4 = 0; k4 < F_IN / 4; ++k4) {
    float4 xv = xr[k4];
    const float* Wr = W + k4 * 4 * HID;
#pragma unroll
    for (int f = 0; f < HID; ++f)
      acc[f] += xv.x * Wr[f] + xv.y * Wr[HID + f] +
                xv.z * Wr[2 * HID + f] + xv.w * Wr[3 * HID + f];
  }
  float as = 0.f, ad = 0.f;
#pragma unroll
  for (int f = 0; f < HID; ++f) { as += acc[f] * atts[f]; ad += acc[f] * attd[f]; }
  float4* hp = (float4*)(h + (size_t)row * HID);
  hp[0] = make_float4(acc[0], acc[1], acc[2], acc[3]);
  hp[1] = make_float4(acc[4], acc[5], acc[6], acc[7]);
  hp[2] = make_float4(acc[8], acc[9], acc[10], acc[11]);
  hp[3] = make_float4(acc[12], acc[13], acc[14], acc[15]);
  as_[row] = as;
  ad_[row] = ad;
}

__global__ __launch_bounds__(256) void k_gemm2(const float* __restrict__ hin,
                                               const float* __restrict__ W,
                                               const float* __restrict__ atts,
                                               const float* __restrict__ attd,
                                               float* __restrict__ h2,
                                               float* __restrict__ as_,
                                               float* __restrict__ ad_) {
  int row = blockIdx.x * 256 + threadIdx.x;
  if (row >= N_NODES) return;
  float hv[HID];
  const float4* hp = (const float4*)(hin + (size_t)row * HID);
#pragma unroll
  for (int j = 0; j < 4; ++j) {
    float4 v = hp[j];
    hv[4 * j] = v.x; hv[4 * j + 1] = v.y; hv[4 * j + 2] = v.z; hv[4 * j + 3] = v.w;
  }
  float acc[NCLS];
#pragma unroll
  for (int f = 0; f < NCLS; ++f) acc[f] = 0.f;
#pragma unroll
  for (int k = 0; k < HID; ++k) {
    float xv = hv[k];
    const float* Wr = W + k * NCLS;
#pragma unroll
    for (int f = 0; f < NCLS; ++f) acc[f] += xv * Wr[f];
  }
  float as = 0.f, ad = 0.f;
#pragma unroll
  for (int f = 0; f < NCLS; ++f) { as += acc[f] * atts[f]; ad += acc[f] * attd[f]; }
  float4* op = (float4*)(h2 + (size_t)row * NCLS);
#pragma unroll
  for (int j = 0; j < 8; ++j)
    op[j] = make_float4(acc[4 * j], acc[4 * j + 1], acc[4 * j + 2], acc[4 * j + 3]);
  as_[row] = as;
  ad_[row] = ad;
}

// ---------- per-node softmax + aggregation (wave per node, no atomics) ----------
template <int D, bool FINAL>
__global__ __launch_bounds__(256) void k_aggregate(const int* __restrict__ offs,
                                                   const int* __restrict__ srcS,
                                                   const float* __restrict__ as_,
                                                   const float* __restrict__ ad_,
                                                   const float* __restrict__ h,
                                                   const float* __restrict__ bias,
                                                   float* __restrict__ out) {
  int node = blockIdx.x * 4 + (threadIdx.x >> 6);
  if (node >= N_NODES) return;
  int lane = threadIdx.x & 63;
  int beg = offs[node];
  int end = offs[node + 1];
  beg = min(max(beg, 0), N_TOT);
  end = min(max(end, beg), N_TOT);
  float ad = ad_[node];

  // pass 1: online softmax stats over incoming edges
  float m = -1e30f, s = 0.f;
  for (int i = beg + lane; i < end; i += 64) {
    int sn = min(max(srcS[i], 0), N_NODES - 1);
    float e = as_[sn] + ad;
    e = e > 0.f ? e : NEG_SLOPE * e;
    float nm = fmaxf(m, e);
    s = s * __expf(m - nm) + __expf(e - nm);
    m = nm;
  }
#pragma unroll
  for (int off = 1; off < 64; off <<= 1) {
    float m2 = __shfl_xor(m, off);
    float s2 = __shfl_xor(s, off);
    float nm = fmaxf(m, m2);
    s = s * __expf(m - nm) + s2 * __expf(m2 - nm);
    m = nm;
  }
  float inv_s = 1.f / s;

  // pass 2: weighted gather-sum, feature-parallel
  constexpr int G = 64 / D;
  int g = lane / D;
  int f = lane % D;
  float acc = 0.f;
  for (int i = beg + g; i < end; i += G) {
    int sn = min(max(srcS[i], 0), N_NODES - 1);
    float e = as_[sn] + ad;
    e = e > 0.f ? e : NEG_SLOPE * e;
    float alpha = __expf(e - m) * inv_s;
    acc += alpha * h[(size_t)sn * D + f];
  }
#pragma unroll
  for (int off = D; off < 64; off <<= 1) acc += __shfl_xor(acc, off);

  float val = acc + bias[f];
  if (!FINAL) {
    if (g == 0) out[(size_t)node * D + f] = fmaxf(val, 0.f);  // relu
  } else {
    float mx = val;
#pragma unroll
    for (int off = 1; off < 32; off <<= 1) mx = fmaxf(mx, __shfl_xor(mx, off));
    float ex = __expf(val - mx);
    float se = ex;
#pragma unroll
    for (int off = 1; off < 32; off <<= 1) se += __shfl_xor(se, off);
    if (g == 0) out[(size_t)node * D + f] = val - mx - __logf(se);
  }
}

extern "C" void kernel_launch(void* const* d_in, const int* in_sizes, int n_in,
                              void* d_out, int out_size, void* d_ws, size_t ws_size,
                              hipStream_t stream) {
  const float* x    = (const float*)d_in[0];
  const int*   ei   = (const int*)d_in[1];
  const float* W1   = (const float*)d_in[2];
  const float* as1w = (const float*)d_in[3];
  const float* ad1w = (const float*)d_in[4];
  const float* b1   = (const float*)d_in[5];
  const float* W2   = (const float*)d_in[6];
  const float* as2w = (const float*)d_in[7];
  const float* ad2w = (const float*)d_in[8];
  const float* b2   = (const float*)d_in[9];
  float* out = (float*)d_out;

  char* w = (char*)d_ws;
  size_t off = 0;
  auto alloc = [&](size_t bytes) -> char* {
    char* p = w + off;
    off += (bytes + 511) & ~(size_t)511;
    return p;
  };
  int*   flag  = (int*)alloc(4);
  int*   bcnt  = (int*)alloc((size_t)NBKT * 4);
  int*   bbase = (int*)alloc((size_t)NBKT * 4);
  int*   cbase = (int*)alloc((size_t)NBKT * 4);
  int*   bcur  = (int*)alloc((size_t)NBKT * 4);
  int*   offs  = (int*)alloc((size_t)(N_NODES + 1) * 4);
  int*   srcS  = (int*)alloc((size_t)N_TOT * 4);

  // binned (12.8MB, packed int per edge) aliases the first 13.6MB of the
  // h-region; binned is dead before k_gemm1 writes h1 (stream-ordered).
  size_t region_begin = off;
  int* binned = (int*)alloc((size_t)N_EDGES * 4);
  off = region_begin;
  float* h1  = (float*)alloc((size_t)N_NODES * HID * 4);
  float* as1 = (float*)alloc((size_t)N_NODES * 4);
  float* ad1 = (float*)alloc((size_t)N_NODES * 4);
  float* hr  = (float*)alloc((size_t)N_NODES * HID * 4);
  float* h2  = (float*)alloc((size_t)N_NODES * NCLS * 4);
  float* as2 = (float*)alloc((size_t)N_NODES * 4);
  float* ad2 = (float*)alloc((size_t)N_NODES * 4);

  hipMemsetAsync(bcnt, 0, (size_t)NBKT * 4, stream);
  k_detect<<<1, 64, 0, stream>>>(ei, flag);
  k_bcount<<<512, 256, 0, stream>>>(ei, flag, bcnt);
  k_bscan<<<1, 256, 0, stream>>>(bcnt, bbase, cbase, bcur, offs);
  k_bin<<<(N_EDGES + 255) / 256, 256, 0, stream>>>(ei, flag, bcur, binned);
  k_bucket<<<NBKT, 256, 0, stream>>>(bcnt, bbase, cbase, binned, offs, srcS);
  k_gemm1<<<(N_NODES + 255) / 256, 256, 0, stream>>>(x, W1, as1w, ad1w, h1, as1, ad1);
  k_aggregate<HID, false><<<N_NODES / 4, 256, 0, stream>>>(offs, srcS, as1, ad1, h1, b1, hr);
  k_gemm2<<<(N_NODES + 255) / 256, 256, 0, stream>>>(hr, W2, as2w, ad2w, h2, as2, ad2);
  k_aggregate<NCLS, true><<<N_NODES / 4, 256, 0, stream>>>(offs, srcS, as2, ad2, h2, b2, out);
}

// Round 4
// 528.275 us; speedup vs baseline: 2.2034x; 2.2034x over previous
//
#include <hip/hip_runtime.h>
#include <math.h>

#define N_NODES 100000
#define N_EDGES 3200000
#define N_TOT   (N_EDGES + N_NODES)
#define F_IN    512
#define HID     16
#define NCLS    32
#define NEG_SLOPE 0.2f

#define BSH   7                       // bucket shift: 128 nodes per bucket
#define NBKT  ((N_NODES + 127) / 128) // 782
#define SRC_MASK 0x1FFFF              // 17 bits, N_NODES < 131072

#define G_GROUPS 512
#define EPG (N_EDGES / G_GROUPS)      // 6250 exact

// ---------- edge dtype detection (int64 vs int32) ----------
__global__ __launch_bounds__(64) void k_detect(const int* __restrict__ ei,
                                               int* __restrict__ flag) {
  int v = ei[2 * threadIdx.x + 1];
  unsigned long long m = __ballot(v != 0);
  if (threadIdx.x == 0) *flag = (m == 0ull) ? 1 : 0;  // 1 => int64 layout
}

// ---------- phase 1: per-group LDS histogram over dst buckets ----------
__global__ __launch_bounds__(256) void k_hist(const int* __restrict__ ei,
                                              const int* __restrict__ flag,
                                              int* __restrict__ H) {
  __shared__ int h[NBKT];
  for (int i = threadIdx.x; i < NBKT; i += 256) h[i] = 0;
  __syncthreads();
  int fl = *flag;
  int g = blockIdx.x;
  int e0 = g * EPG, e1 = e0 + EPG;
  for (int e = e0 + threadIdx.x; e < e1; e += 256) {
    int d = fl ? ei[2 * (N_EDGES + e)] : ei[N_EDGES + e];
    d = min(max(d, 0), N_NODES - 1);
    atomicAdd(&h[d >> BSH], 1);
  }
  __syncthreads();
  int* Hrow = H + (size_t)g * NBKT;
  for (int i = threadIdx.x; i < NBKT; i += 256) Hrow[i] = h[i];
}

// ---------- phase 2a: per-bucket exclusive scan over groups ----------
__global__ __launch_bounds__(G_GROUPS) void k_colscan(int* __restrict__ H,
                                                      int* __restrict__ tot) {
  __shared__ int s[G_GROUPS];
  int b = blockIdx.x, t = threadIdx.x;
  int v = H[(size_t)t * NBKT + b];
  s[t] = v;
  __syncthreads();
  for (int off = 1; off < G_GROUPS; off <<= 1) {
    int a = (t >= off) ? s[t - off] : 0;
    __syncthreads();
    s[t] += a;
    __syncthreads();
  }
  H[(size_t)t * NBKT + b] = s[t] - v;     // exclusive prefix within bucket
  if (t == G_GROUPS - 1) tot[b] = s[t];   // bucket total
}

// ---------- phase 2b: scan bucket totals (256 threads, 4 buckets/thread) ----------
__global__ __launch_bounds__(256) void k_bscan(const int* __restrict__ tot,
                                               int* __restrict__ bbase,
                                               int* __restrict__ cbase,
                                               int* __restrict__ offs) {
  __shared__ int s1[256], s2[256];
  int t = threadIdx.x;
  int c[4], vn[4];
  int sum1 = 0, sum2 = 0;
#pragma unroll
  for (int j = 0; j < 4; ++j) {
    int idx = t * 4 + j;
    int cc = 0, vv = 0;
    if (idx < NBKT) {
      cc = tot[idx];
      int lo = idx << BSH;
      vv = min(128, N_NODES - lo);     // valid nodes in bucket (self loops)
    }
    c[j] = cc; vn[j] = vv;
    sum1 += cc; sum2 += cc + vv;
  }
  int o1 = sum1, o2 = sum2;
  s1[t] = sum1; s2[t] = sum2;
  __syncthreads();
  for (int off = 1; off < 256; off <<= 1) {
    int a = 0, b = 0;
    if (t >= off) { a = s1[t - off]; b = s2[t - off]; }
    __syncthreads();
    s1[t] += a; s2[t] += b;
    __syncthreads();
  }
  int r1 = s1[t] - o1;
  int r2 = s2[t] - o2;
#pragma unroll
  for (int j = 0; j < 4; ++j) {
    int idx = t * 4 + j;
    if (idx < NBKT) {
      bbase[idx] = r1; cbase[idx] = r2;
      r1 += c[j];
      r2 += c[j] + vn[j];
    }
  }
  if (t == 0) offs[N_NODES] = N_TOT;
}

// ---------- phase 3: rank-scatter into bucket bins (LDS cursors only) ----------
__global__ __launch_bounds__(256) void k_scatter(const int* __restrict__ ei,
                                                 const int* __restrict__ flag,
                                                 const int* __restrict__ H,
                                                 const int* __restrict__ bbase,
                                                 int* __restrict__ binned) {
  __shared__ int cur[NBKT];
  int g = blockIdx.x, t = threadIdx.x;
  const int* Hrow = H + (size_t)g * NBKT;
  for (int i = t; i < NBKT; i += 256) cur[i] = bbase[i] + Hrow[i];
  __syncthreads();
  int fl = *flag;
  int e0 = g * EPG, e1 = e0 + EPG;
  for (int e = e0 + t; e < e1; e += 256) {
    int s, d;
    if (fl) { s = ei[2 * e]; d = ei[2 * (N_EDGES + e)]; }
    else    { s = ei[e];     d = ei[N_EDGES + e]; }
    s = min(max(s, 0), N_NODES - 1);
    d = min(max(d, 0), N_NODES - 1);
    int p = atomicAdd(&cur[d >> BSH], 1);
    p = min(max(p, 0), N_EDGES - 1);
    binned[p] = ((d & 127) << 17) | s;
  }
}

// ---------- per-bucket counting sort in LDS -> CSR offs + srcS ----------
__global__ __launch_bounds__(256) void k_bucket(const int* __restrict__ tot,
                                                const int* __restrict__ bbase,
                                                const int* __restrict__ cbase,
                                                const int* __restrict__ binned,
                                                int* __restrict__ offs,
                                                int* __restrict__ srcS) {
  __shared__ int cnt[128], cur[128], sc[128];
  __shared__ int hdr[3];
  int b = blockIdx.x, t = threadIdx.x;
  if (t == 0) {
    hdr[0] = min(max(tot[b], 0), N_EDGES);
    hdr[1] = min(max(bbase[b], 0), N_EDGES - 1);
    hdr[2] = min(max(cbase[b], 0), N_TOT - 1);
  }
  if (t < 128) cnt[t] = 0;
  __syncthreads();
  int nb = hdr[0], base = hdr[1], cb = hdr[2];

  for (int i = t; i < nb; i += 256) {
    int pk = binned[min(base + i, N_EDGES - 1)];
    atomicAdd(&cnt[(pk >> 17) & 127], 1);
  }
  __syncthreads();

  int node = (b << BSH) + t;
  int myv = 0;
  if (t < 128) myv = (node < N_NODES) ? cnt[t] + 1 : 0;  // +1 self loop
  if (t < 128) sc[t] = myv;
  __syncthreads();
  for (int off = 1; off < 128; off <<= 1) {
    int v = 0;
    if (t < 128 && t >= off) v = sc[t - off];
    __syncthreads();
    if (t < 128) sc[t] += v;
    __syncthreads();
  }
  if (t < 128 && node < N_NODES) {
    int lofs = sc[t] - myv;          // exclusive prefix within bucket
    int o = min(cb + lofs, N_TOT - 1);
    offs[node] = o;
    srcS[o] = node;                  // self-loop occupies slot 0
    cur[t] = lofs + 1;
  }
  __syncthreads();

  for (int i = t; i < nb; i += 256) {
    int pk = binned[min(base + i, N_EDGES - 1)];
    int p = atomicAdd(&cur[(pk >> 17) & 127], 1);
    srcS[min(cb + p, N_TOT - 1)] = pk & SRC_MASK;
  }
}

// ---------- layer GEMMs (thread-per-row; W uniform -> s_load path) ----------
__global__ __launch_bounds__(256) void k_gemm1(const float* __restrict__ x,
                                               const float* __restrict__ W,
                                               const float* __restrict__ atts,
                                               const float* __restrict__ attd,
                                               float* __restrict__ h,
                                               float* __restrict__ as_,
                                               float* __restrict__ ad_) {
  int row = blockIdx.x * 256 + threadIdx.x;
  if (row >= N_NODES) return;
  const float4* xr = (const float4*)(x + (size_t)row * F_IN);
  float acc[HID];
#pragma unroll
  for (int f = 0; f < HID; ++f) acc[f] = 0.f;
  for (int k4 = 0; k4 < F_IN / 4; ++k4) {
    float4 xv = xr[k4];
    const float* Wr = W + k4 * 4 * HID;
#pragma unroll
    for (int f = 0; f < HID; ++f)
      acc[f] += xv.x * Wr[f] + xv.y * Wr[HID + f] +
                xv.z * Wr[2 * HID + f] + xv.w * Wr[3 * HID + f];
  }
  float as = 0.f, ad = 0.f;
#pragma unroll
  for (int f = 0; f < HID; ++f) { as += acc[f] * atts[f]; ad += acc[f] * attd[f]; }
  float4* hp = (float4*)(h + (size_t)row * HID);
  hp[0] = make_float4(acc[0], acc[1], acc[2], acc[3]);
  hp[1] = make_float4(acc[4], acc[5], acc[6], acc[7]);
  hp[2] = make_float4(acc[8], acc[9], acc[10], acc[11]);
  hp[3] = make_float4(acc[12], acc[13], acc[14], acc[15]);
  as_[row] = as;
  ad_[row] = ad;
}

__global__ __launch_bounds__(256) void k_gemm2(const float* __restrict__ hin,
                                               const float* __restrict__ W,
                                               const float* __restrict__ atts,
                                               const float* __restrict__ attd,
                                               float* __restrict__ h2,
                                               float* __restrict__ as_,
                                               float* __restrict__ ad_) {
  int row = blockIdx.x * 256 + threadIdx.x;
  if (row >= N_NODES) return;
  float hv[HID];
  const float4* hp = (const float4*)(hin + (size_t)row * HID);
#pragma unroll
  for (int j = 0; j < 4; ++j) {
    float4 v = hp[j];
    hv[4 * j] = v.x; hv[4 * j + 1] = v.y; hv[4 * j + 2] = v.z; hv[4 * j + 3] = v.w;
  }
  float acc[NCLS];
#pragma unroll
  for (int f = 0; f < NCLS; ++f) acc[f] = 0.f;
#pragma unroll
  for (int k = 0; k < HID; ++k) {
    float xv = hv[k];
    const float* Wr = W + k * NCLS;
#pragma unroll
    for (int f = 0; f < NCLS; ++f) acc[f] += xv * Wr[f];
  }
  float as = 0.f, ad = 0.f;
#pragma unroll
  for (int f = 0; f < NCLS; ++f) { as += acc[f] * atts[f]; ad += acc[f] * attd[f]; }
  float4* op = (float4*)(h2 + (size_t)row * NCLS);
#pragma unroll
  for (int j = 0; j < 8; ++j)
    op[j] = make_float4(acc[4 * j], acc[4 * j + 1], acc[4 * j + 2], acc[4 * j + 3]);
  as_[row] = as;
  ad_[row] = ad;
}

// ---------- per-node softmax + aggregation (wave per node, no atomics) ----------
template <int D, bool FINAL>
__global__ __launch_bounds__(256) void k_aggregate(const int* __restrict__ offs,
                                                   const int* __restrict__ srcS,
                                                   const float* __restrict__ as_,
                                                   const float* __restrict__ ad_,
                                                   const float* __restrict__ h,
                                                   const float* __restrict__ bias,
                                                   float* __restrict__ out) {
  int node = blockIdx.x * 4 + (threadIdx.x >> 6);
  if (node >= N_NODES) return;
  int lane = threadIdx.x & 63;
  int beg = offs[node];
  int end = offs[node + 1];
  beg = min(max(beg, 0), N_TOT);
  end = min(max(end, beg), N_TOT);
  float ad = ad_[node];

  // pass 1: online softmax stats over incoming edges
  float m = -1e30f, s = 0.f;
  for (int i = beg + lane; i < end; i += 64) {
    int sn = min(max(srcS[i], 0), N_NODES - 1);
    float e = as_[sn] + ad;
    e = e > 0.f ? e : NEG_SLOPE * e;
    float nm = fmaxf(m, e);
    s = s * __expf(m - nm) + __expf(e - nm);
    m = nm;
  }
#pragma unroll
  for (int off = 1; off < 64; off <<= 1) {
    float m2 = __shfl_xor(m, off);
    float s2 = __shfl_xor(s, off);
    float nm = fmaxf(m, m2);
    s = s * __expf(m - nm) + s2 * __expf(m2 - nm);
    m = nm;
  }
  float inv_s = 1.f / s;

  // pass 2: weighted gather-sum, feature-parallel
  constexpr int G = 64 / D;
  int g = lane / D;
  int f = lane % D;
  float acc = 0.f;
  for (int i = beg + g; i < end; i += G) {
    int sn = min(max(srcS[i], 0), N_NODES - 1);
    float e = as_[sn] + ad;
    e = e > 0.f ? e : NEG_SLOPE * e;
    float alpha = __expf(e - m) * inv_s;
    acc += alpha * h[(size_t)sn * D + f];
  }
#pragma unroll
  for (int off = D; off < 64; off <<= 1) acc += __shfl_xor(acc, off);

  float val = acc + bias[f];
  if (!FINAL) {
    if (g == 0) out[(size_t)node * D + f] = fmaxf(val, 0.f);  // relu
  } else {
    float mx = val;
#pragma unroll
    for (int off = 1; off < 32; off <<= 1) mx = fmaxf(mx, __shfl_xor(mx, off));
    float ex = __expf(val - mx);
    float se = ex;
#pragma unroll
    for (int off = 1; off < 32; off <<= 1) se += __shfl_xor(se, off);
    if (g == 0) out[(size_t)node * D + f] = val - mx - __logf(se);
  }
}

extern "C" void kernel_launch(void* const* d_in, const int* in_sizes, int n_in,
                              void* d_out, int out_size, void* d_ws, size_t ws_size,
                              hipStream_t stream) {
  const float* x    = (const float*)d_in[0];
  const int*   ei   = (const int*)d_in[1];
  const float* W1   = (const float*)d_in[2];
  const float* as1w = (const float*)d_in[3];
  const float* ad1w = (const float*)d_in[4];
  const float* b1   = (const float*)d_in[5];
  const float* W2   = (const float*)d_in[6];
  const float* as2w = (const float*)d_in[7];
  const float* ad2w = (const float*)d_in[8];
  const float* b2   = (const float*)d_in[9];
  float* out = (float*)d_out;

  char* w = (char*)d_ws;
  size_t off = 0;
  auto alloc = [&](size_t bytes) -> char* {
    char* p = w + off;
    off += (bytes + 511) & ~(size_t)511;
    return p;
  };
  int*   flag  = (int*)alloc(4);
  int*   tot   = (int*)alloc((size_t)NBKT * 4);
  int*   bbase = (int*)alloc((size_t)NBKT * 4);
  int*   cbase = (int*)alloc((size_t)NBKT * 4);
  int*   offs  = (int*)alloc((size_t)(N_NODES + 1) * 4);
  int*   srcS  = (int*)alloc((size_t)N_TOT * 4);

  // union region: {binned 12.8MB + H 1.6MB} (CSR build) vs h-arrays (layers).
  // binned/H are dead before k_gemm1 writes h1 (stream-ordered).
  size_t region_begin = off;
  int* binned = (int*)alloc((size_t)N_EDGES * 4);
  int* H      = (int*)alloc((size_t)G_GROUPS * NBKT * 4);
  off = region_begin;
  float* h1  = (float*)alloc((size_t)N_NODES * HID * 4);
  float* as1 = (float*)alloc((size_t)N_NODES * 4);
  float* ad1 = (float*)alloc((size_t)N_NODES * 4);
  float* hr  = (float*)alloc((size_t)N_NODES * HID * 4);
  float* h2  = (float*)alloc((size_t)N_NODES * NCLS * 4);
  float* as2 = (float*)alloc((size_t)N_NODES * 4);
  float* ad2 = (float*)alloc((size_t)N_NODES * 4);

  k_detect<<<1, 64, 0, stream>>>(ei, flag);
  k_hist<<<G_GROUPS, 256, 0, stream>>>(ei, flag, H);
  k_colscan<<<NBKT, G_GROUPS, 0, stream>>>(H, tot);
  k_bscan<<<1, 256, 0, stream>>>(tot, bbase, cbase, offs);
  k_scatter<<<G_GROUPS, 256, 0, stream>>>(ei, flag, H, bbase, binned);
  k_bucket<<<NBKT, 256, 0, stream>>>(tot, bbase, cbase, binned, offs, srcS);
  k_gemm1<<<(N_NODES + 255) / 256, 256, 0, stream>>>(x, W1, as1w, ad1w, h1, as1, ad1);
  k_aggregate<HID, false><<<N_NODES / 4, 256, 0, stream>>>(offs, srcS, as1, ad1, h1, b1, hr);
  k_gemm2<<<(N_NODES + 255) / 256, 256, 0, stream>>>(hr, W2, as2w, ad2w, h2, as2, ad2);
  k_aggregate<NCLS, true><<<N_NODES / 4, 256, 0, stream>>>(offs, srcS, as2, ad2, h2, b2, out);
}

// Round 6
// 350.441 us; speedup vs baseline: 3.3216x; 1.5075x over previous
//
#include <hip/hip_runtime.h>
#include <math.h>

#define N_NODES 100000
#define N_EDGES 3200000
#define N_TOT   (N_EDGES + N_NODES)
#define F_IN    512
#define HID     16
#define NCLS    32
#define NEG_SLOPE 0.2f

#define BSH   7                       // bucket shift: 128 nodes per bucket
#define NBKT  ((N_NODES + 127) / 128) // 782
#define SRC_MASK 0x1FFFF              // 17 bits, N_NODES < 131072

#define G_GROUPS 512
#define EPG (N_EDGES / G_GROUPS)      // 6250 exact

// ---------- edge dtype detection (int64 vs int32) ----------
__global__ __launch_bounds__(64) void k_detect(const int* __restrict__ ei,
                                               int* __restrict__ flag) {
  int v = ei[2 * threadIdx.x + 1];
  unsigned long long m = __ballot(v != 0);
  if (threadIdx.x == 0) *flag = (m == 0ull) ? 1 : 0;  // 1 => int64 layout
}

// ---------- phase 1: per-group LDS histogram over dst buckets ----------
__global__ __launch_bounds__(256) void k_hist(const int* __restrict__ ei,
                                              const int* __restrict__ flag,
                                              int* __restrict__ H) {
  __shared__ int h[NBKT];
  for (int i = threadIdx.x; i < NBKT; i += 256) h[i] = 0;
  __syncthreads();
  int fl = *flag;
  int g = blockIdx.x;
  int e0 = g * EPG, e1 = e0 + EPG;
  for (int e = e0 + threadIdx.x; e < e1; e += 256) {
    int d = fl ? ei[2 * (N_EDGES + e)] : ei[N_EDGES + e];
    d = min(max(d, 0), N_NODES - 1);
    atomicAdd(&h[d >> BSH], 1);
  }
  __syncthreads();
  int* Hrow = H + (size_t)g * NBKT;
  for (int i = threadIdx.x; i < NBKT; i += 256) Hrow[i] = h[i];
}

// ---------- phase 2a: per-bucket exclusive scan over groups ----------
__global__ __launch_bounds__(G_GROUPS) void k_colscan(int* __restrict__ H,
                                                      int* __restrict__ tot) {
  __shared__ int s[G_GROUPS];
  int b = blockIdx.x, t = threadIdx.x;
  int v = H[(size_t)t * NBKT + b];
  s[t] = v;
  __syncthreads();
  for (int off = 1; off < G_GROUPS; off <<= 1) {
    int a = (t >= off) ? s[t - off] : 0;
    __syncthreads();
    s[t] += a;
    __syncthreads();
  }
  H[(size_t)t * NBKT + b] = s[t] - v;     // exclusive prefix within bucket
  if (t == G_GROUPS - 1) tot[b] = s[t];   // bucket total
}

// ---------- phase 2b: scan bucket totals ----------
__global__ __launch_bounds__(256) void k_bscan(const int* __restrict__ tot,
                                               int* __restrict__ bbase,
                                               int* __restrict__ cbase,
                                               int* __restrict__ offs) {
  __shared__ int s1[256], s2[256];
  int t = threadIdx.x;
  int c[4], vn[4];
  int sum1 = 0, sum2 = 0;
#pragma unroll
  for (int j = 0; j < 4; ++j) {
    int idx = t * 4 + j;
    int cc = 0, vv = 0;
    if (idx < NBKT) {
      cc = tot[idx];
      int lo = idx << BSH;
      vv = min(128, N_NODES - lo);
    }
    c[j] = cc; vn[j] = vv;
    sum1 += cc; sum2 += cc + vv;
  }
  int o1 = sum1, o2 = sum2;
  s1[t] = sum1; s2[t] = sum2;
  __syncthreads();
  for (int off = 1; off < 256; off <<= 1) {
    int a = 0, b = 0;
    if (t >= off) { a = s1[t - off]; b = s2[t - off]; }
    __syncthreads();
    s1[t] += a; s2[t] += b;
    __syncthreads();
  }
  int r1 = s1[t] - o1;
  int r2 = s2[t] - o2;
#pragma unroll
  for (int j = 0; j < 4; ++j) {
    int idx = t * 4 + j;
    if (idx < NBKT) {
      bbase[idx] = r1; cbase[idx] = r2;
      r1 += c[j];
      r2 += c[j] + vn[j];
    }
  }
  if (t == 0) offs[N_NODES] = N_TOT;
}

// ---------- phase 3: rank-scatter into bucket bins (LDS cursors only) ----------
__global__ __launch_bounds__(256) void k_scatter(const int* __restrict__ ei,
                                                 const int* __restrict__ flag,
                                                 const int* __restrict__ H,
                                                 const int* __restrict__ bbase,
                                                 int* __restrict__ binned) {
  __shared__ int cur[NBKT];
  int g = blockIdx.x, t = threadIdx.x;
  const int* Hrow = H + (size_t)g * NBKT;
  for (int i = t; i < NBKT; i += 256) cur[i] = bbase[i] + Hrow[i];
  __syncthreads();
  int fl = *flag;
  int e0 = g * EPG, e1 = e0 + EPG;
  for (int e = e0 + t; e < e1; e += 256) {
    int s, d;
    if (fl) { s = ei[2 * e]; d = ei[2 * (N_EDGES + e)]; }
    else    { s = ei[e];     d = ei[N_EDGES + e]; }
    s = min(max(s, 0), N_NODES - 1);
    d = min(max(d, 0), N_NODES - 1);
    int p = atomicAdd(&cur[d >> BSH], 1);
    p = min(max(p, 0), N_EDGES - 1);
    binned[p] = ((d & 127) << 17) | s;
  }
}

// ---------- per-bucket counting sort in LDS -> CSR offs + srcS ----------
__global__ __launch_bounds__(256) void k_bucket(const int* __restrict__ tot,
                                                const int* __restrict__ bbase,
                                                const int* __restrict__ cbase,
                                                const int* __restrict__ binned,
                                                int* __restrict__ offs,
                                                int* __restrict__ srcS) {
  __shared__ int cnt[128], cur[128], sc[128];
  __shared__ int hdr[3];
  int b = blockIdx.x, t = threadIdx.x;
  if (t == 0) {
    hdr[0] = min(max(tot[b], 0), N_EDGES);
    hdr[1] = min(max(bbase[b], 0), N_EDGES - 1);
    hdr[2] = min(max(cbase[b], 0), N_TOT - 1);
  }
  if (t < 128) cnt[t] = 0;
  __syncthreads();
  int nb = hdr[0], base = hdr[1], cb = hdr[2];

  for (int i = t; i < nb; i += 256) {
    int pk = binned[min(base + i, N_EDGES - 1)];
    atomicAdd(&cnt[(pk >> 17) & 127], 1);
  }
  __syncthreads();

  int node = (b << BSH) + t;
  int myv = 0;
  if (t < 128) myv = (node < N_NODES) ? cnt[t] + 1 : 0;  // +1 self loop
  if (t < 128) sc[t] = myv;
  __syncthreads();
  for (int off = 1; off < 128; off <<= 1) {
    int v = 0;
    if (t < 128 && t >= off) v = sc[t - off];
    __syncthreads();
    if (t < 128) sc[t] += v;
    __syncthreads();
  }
  if (t < 128 && node < N_NODES) {
    int lofs = sc[t] - myv;
    int o = min(cb + lofs, N_TOT - 1);
    offs[node] = o;
    srcS[o] = node;                  // self-loop occupies slot 0
    cur[t] = lofs + 1;
  }
  __syncthreads();

  for (int i = t; i < nb; i += 256) {
    int pk = binned[min(base + i, N_EDGES - 1)];
    int p = atomicAdd(&cur[(pk >> 17) & 127], 1);
    srcS[min(cb + p, N_TOT - 1)] = pk & SRC_MASK;
  }
}

// ---------- tiny prep: ws2 = W2 @ att_src2, wd2 = W2 @ att_dst2 ----------
__global__ __launch_bounds__(64) void k_prep(const float* __restrict__ W2,
                                             const float* __restrict__ as2w,
                                             const float* __restrict__ ad2w,
                                             float* __restrict__ ws2,
                                             float* __restrict__ wd2) {
  int t = threadIdx.x;
  if (t < HID) {
    float s = 0.f, d = 0.f;
    for (int c = 0; c < NCLS; ++c) {
      float wv = W2[t * NCLS + c];
      s += wv * as2w[c];
      d += wv * ad2w[c];
    }
    ws2[t] = s;
    wd2[t] = d;
  }
}

// ---------- layer-1 GEMM (thread-per-row) ----------
__global__ __launch_bounds__(256) void k_gemm1(const float* __restrict__ x,
                                               const float* __restrict__ W,
                                               const float* __restrict__ atts,
                                               const float* __restrict__ attd,
                                               float* __restrict__ h,
                                               float* __restrict__ as_,
                                               float* __restrict__ ad_) {
  int row = blockIdx.x * 256 + threadIdx.x;
  if (row >= N_NODES) return;
  const float4* xr = (const float4*)(x + (size_t)row * F_IN);
  float acc[HID];
#pragma unroll
  for (int f = 0; f < HID; ++f) acc[f] = 0.f;
  for (int k4 = 0; k4 < F_IN / 4; ++k4) {
    float4 xv = xr[k4];
    const float* Wr = W + k4 * 4 * HID;
#pragma unroll
    for (int f = 0; f < HID; ++f)
      acc[f] += xv.x * Wr[f] + xv.y * Wr[HID + f] +
                xv.z * Wr[2 * HID + f] + xv.w * Wr[3 * HID + f];
  }
  float as = 0.f, ad = 0.f;
#pragma unroll
  for (int f = 0; f < HID; ++f) { as += acc[f] * atts[f]; ad += acc[f] * attd[f]; }
  float4* hp = (float4*)(h + (size_t)row * HID);
  hp[0] = make_float4(acc[0], acc[1], acc[2], acc[3]);
  hp[1] = make_float4(acc[4], acc[5], acc[6], acc[7]);
  hp[2] = make_float4(acc[8], acc[9], acc[10], acc[11]);
  hp[3] = make_float4(acc[12], acc[13], acc[14], acc[15]);
  as_[row] = as;
  ad_[row] = ad;
}

// ---------- fused aggregate: single-sweep softmax+gather, D=16 ----------
// All __shfl calls execute with the FULL wave active (divergent-source
// ds_bpermute returns undefined data for inactive source lanes — the
// round-5 bug). Only the accumulate is predicated.
template <bool LAYER1>
__global__ __launch_bounds__(256) void k_agg(const int* __restrict__ offs,
                                             const int* __restrict__ srcS,
                                             const float* __restrict__ as_,
                                             const float* __restrict__ ad_,
                                             const float* __restrict__ h,
                                             const float* __restrict__ b1,
                                             const float* __restrict__ ws2,
                                             const float* __restrict__ wd2,
                                             float* __restrict__ outv,
                                             float* __restrict__ as2,
                                             float* __restrict__ ad2) {
  int node = blockIdx.x * 4 + (threadIdx.x >> 6);
  if (node >= N_NODES) return;
  int lane = threadIdx.x & 63;
  int g = lane >> 4;        // 4 edge groups
  int f = lane & 15;        // feature
  int beg = offs[node];
  int end = offs[node + 1];
  beg = min(max(beg, 0), N_TOT);
  end = min(max(end, beg), N_TOT);
  float ad = ad_[node];

  float s_lane = 0.f;
  float acc = 0.f;
  for (int i0 = beg; i0 < end; i0 += 64) {
    int nb = min(64, end - i0);
    int sn = 0;
    float p = 0.f;
    if (lane < nb) {
      sn = min(max(srcS[i0 + lane], 0), N_NODES - 1);
      float e = as_[sn] + ad;
      e = e > 0.f ? e : NEG_SLOPE * e;
      p = __expf(e);           // no max-shift: |e| <= ~12, exp safe in fp32
    }
    s_lane += p;
    int steps = (nb + 3) >> 2;
    for (int t = 0; t < steps; ++t) {
      int j = g + 4 * t;
      int jj = min(j, nb - 1);          // clamp so source lane is valid
      float alpha = __shfl(p, jj);      // full wave active here
      int snj = __shfl(sn, jj);
      if (j < nb) acc += alpha * h[(size_t)snj * HID + f];
    }
  }
  // total denom across all 64 lanes
#pragma unroll
  for (int off = 1; off < 64; off <<= 1) s_lane += __shfl_xor(s_lane, off);
  // feature sum across the 4 groups
  acc += __shfl_xor(acc, 16);
  acc += __shfl_xor(acc, 32);
  float inv_s = 1.f / s_lane;

  if (LAYER1) {
    float val = fmaxf(acc * inv_s + b1[f], 0.f);   // +bias, relu
    if (g == 0) outv[(size_t)node * HID + f] = val;
    // fused layer-2 attention scores: as2 = hr_row . ws2, ad2 = hr_row . wd2
    float rs = val * ws2[f];
    float rd = val * wd2[f];
#pragma unroll
    for (int off = 1; off < 16; off <<= 1) {
      rs += __shfl_xor(rs, off);
      rd += __shfl_xor(rd, off);
    }
    if (lane == 0) { as2[node] = rs; ad2[node] = rd; }
  } else {
    if (g == 0) outv[(size_t)node * HID + f] = acc * inv_s;
  }
}

// ---------- final: out = log_softmax(agg2 @ W2 + b2), thread-per-node ----------
__global__ __launch_bounds__(256) void k_out(const float* __restrict__ agg2,
                                             const float* __restrict__ W2,
                                             const float* __restrict__ b2,
                                             float* __restrict__ out) {
  int row = blockIdx.x * 256 + threadIdx.x;
  if (row >= N_NODES) return;
  float hv[HID];
  const float4* hp = (const float4*)(agg2 + (size_t)row * HID);
#pragma unroll
  for (int j = 0; j < 4; ++j) {
    float4 v = hp[j];
    hv[4 * j] = v.x; hv[4 * j + 1] = v.y; hv[4 * j + 2] = v.z; hv[4 * j + 3] = v.w;
  }
  float acc[NCLS];
#pragma unroll
  for (int c = 0; c < NCLS; ++c) acc[c] = b2[c];
#pragma unroll
  for (int k = 0; k < HID; ++k) {
    float xv = hv[k];
    const float* Wr = W2 + k * NCLS;
#pragma unroll
    for (int c = 0; c < NCLS; ++c) acc[c] += xv * Wr[c];
  }
  float mx = -1e30f;
#pragma unroll
  for (int c = 0; c < NCLS; ++c) mx = fmaxf(mx, acc[c]);
  float se = 0.f;
#pragma unroll
  for (int c = 0; c < NCLS; ++c) se += __expf(acc[c] - mx);
  float lse = mx + __logf(se);
  float4* op = (float4*)(out + (size_t)row * NCLS);
#pragma unroll
  for (int j = 0; j < 8; ++j)
    op[j] = make_float4(acc[4 * j] - lse, acc[4 * j + 1] - lse,
                        acc[4 * j + 2] - lse, acc[4 * j + 3] - lse);
}

extern "C" void kernel_launch(void* const* d_in, const int* in_sizes, int n_in,
                              void* d_out, int out_size, void* d_ws, size_t ws_size,
                              hipStream_t stream) {
  const float* x    = (const float*)d_in[0];
  const int*   ei   = (const int*)d_in[1];
  const float* W1   = (const float*)d_in[2];
  const float* as1w = (const float*)d_in[3];
  const float* ad1w = (const float*)d_in[4];
  const float* b1   = (const float*)d_in[5];
  const float* W2   = (const float*)d_in[6];
  const float* as2w = (const float*)d_in[7];
  const float* ad2w = (const float*)d_in[8];
  const float* b2   = (const float*)d_in[9];
  float* out = (float*)d_out;

  char* w = (char*)d_ws;
  size_t off = 0;
  auto alloc = [&](size_t bytes) -> char* {
    char* p = w + off;
    off += (bytes + 511) & ~(size_t)511;
    return p;
  };
  int*   flag  = (int*)alloc(4);
  int*   tot   = (int*)alloc((size_t)NBKT * 4);
  int*   bbase = (int*)alloc((size_t)NBKT * 4);
  int*   cbase = (int*)alloc((size_t)NBKT * 4);
  int*   offs  = (int*)alloc((size_t)(N_NODES + 1) * 4);
  int*   srcS  = (int*)alloc((size_t)N_TOT * 4);
  float* ws2   = (float*)alloc((size_t)HID * 4);
  float* wd2   = (float*)alloc((size_t)HID * 4);

  // union region: {binned 12.8MB + H 1.6MB} (CSR build) vs layer arrays.
  // binned/H are dead before k_gemm1 writes h1 (stream-ordered).
  size_t region_begin = off;
  int* binned = (int*)alloc((size_t)N_EDGES * 4);
  int* H      = (int*)alloc((size_t)G_GROUPS * NBKT * 4);
  off = region_begin;
  float* h1   = (float*)alloc((size_t)N_NODES * HID * 4);
  float* as1  = (float*)alloc((size_t)N_NODES * 4);
  float* ad1  = (float*)alloc((size_t)N_NODES * 4);
  float* hr   = (float*)alloc((size_t)N_NODES * HID * 4);
  float* agg2 = (float*)alloc((size_t)N_NODES * HID * 4);
  float* as2  = (float*)alloc((size_t)N_NODES * 4);
  float* ad2  = (float*)alloc((size_t)N_NODES * 4);

  k_detect<<<1, 64, 0, stream>>>(ei, flag);
  k_hist<<<G_GROUPS, 256, 0, stream>>>(ei, flag, H);
  k_colscan<<<NBKT, G_GROUPS, 0, stream>>>(H, tot);
  k_bscan<<<1, 256, 0, stream>>>(tot, bbase, cbase, offs);
  k_scatter<<<G_GROUPS, 256, 0, stream>>>(ei, flag, H, bbase, binned);
  k_bucket<<<NBKT, 256, 0, stream>>>(tot, bbase, cbase, binned, offs, srcS);
  k_gemm1<<<(N_NODES + 255) / 256, 256, 0, stream>>>(x, W1, as1w, ad1w, h1, as1, ad1);
  k_prep<<<1, 64, 0, stream>>>(W2, as2w, ad2w, ws2, wd2);
  k_agg<true><<<(N_NODES + 3) / 4, 256, 0, stream>>>(offs, srcS, as1, ad1, h1,
                                                     b1, ws2, wd2, hr, as2, ad2);
  k_agg<false><<<(N_NODES + 3) / 4, 256, 0, stream>>>(offs, srcS, as2, ad2, hr,
                                                      nullptr, nullptr, nullptr,
                                                      agg2, nullptr, nullptr);
  k_out<<<(N_NODES + 255) / 256, 256, 0, stream>>>(agg2, W2, b2, out);
}